// Round 9
// baseline (224.522 us; speedup 1.0000x reference)
//
#include <hip/hip_runtime.h>
#include <hip/hip_bf16.h>

// Problem constants (GraphConv: B=4, C=64, N=16384, K=32)
#define BB 4
#define CC 64
#define NN 16384
#define KK 32
#define PTS (BB * NN)   // 65536 points
#define NB3 512         // total BN partial slots (128 points each)

// ---- bf16 helpers (RNE pack, cheap unpack) --------------------------------
static __device__ __forceinline__ unsigned short f2bf(float f) {
    unsigned u = __builtin_bit_cast(unsigned, f);
    unsigned r = (u + 0x7fffu + ((u >> 16) & 1u)) >> 16;   // round-nearest-even
    return (unsigned short)r;
}
static __device__ __forceinline__ float bflo(unsigned u) {
    return __builtin_bit_cast(float, u << 16);
}
static __device__ __forceinline__ float bfhi(unsigned u) {
    return __builtin_bit_cast(float, u & 0xffff0000u);
}

// ---------------------------------------------------------------------------
// k1 (v3): zt[bl][n][o] (bf16x2-packed) = sum_c W[o][c] * x[b][c][n].
//   64-point chunk per block; lane = point; wave w computes o in [16w,16w+16).
//   W row pointer forced wave-uniform via readfirstlane -> s_load on the
//   scalar pipe, VALU does pure FMA from registers. Output packed to bf16
//   pairs and transposed through LDS (stride 33: conflict-free writes).
// ---------------------------------------------------------------------------
template <int ZB>
__global__ __launch_bounds__(256) void k1_wx_t(const float* __restrict__ x,
                                               const float* __restrict__ W,
                                               unsigned* __restrict__ ztu,
                                               int b0) {
    __shared__ float    xs[64 * 65];     // 16.6 KB
    __shared__ unsigned zsu[64 * 33];    // 8.4 KB (point-major, bf16x2)
    const int tid  = threadIdx.x;
    const int lane = tid & 63;
    const int w    = tid >> 6;
    const int chunk = blockIdx.x;        // ZB*256 chunks of 64 points
    const int bl = chunk >> 8;           // local batch
    const int b  = b0 + bl;              // global batch
    const int n0 = (chunk & 255) << 6;

    // stage x[b][0:64][n0:n0+64] (coalesced 256B rows)
    const float* xb = x + (size_t)b * CC * NN + n0;
#pragma unroll
    for (int i = 0; i < 16; ++i) {
        const int c = i * 4 + w;
        xs[c * 65 + lane] = xb[(size_t)c * NN + lane];
    }
    __syncthreads();

    float xr[64];
#pragma unroll
    for (int c = 0; c < 64; ++c) xr[c] = xs[c * 65 + lane];

    float acc[16];
#pragma unroll
    for (int i = 0; i < 16; ++i) {
        const int o = w * 16 + i;
        // force wave-uniform scalar pointer (o is wave-uniform: w = tid>>6)
        const unsigned long long wa = (unsigned long long)(const void*)(W + (o << 6));
        const unsigned plo = __builtin_amdgcn_readfirstlane((unsigned)wa);
        const unsigned phi = __builtin_amdgcn_readfirstlane((unsigned)(wa >> 32));
        const float* wrow = (const float*)(((unsigned long long)phi << 32) | plo);
        float a0 = 0.f, a1 = 0.f, a2 = 0.f, a3 = 0.f;
#pragma unroll
        for (int c = 0; c < 64; c += 4) {
            a0 = fmaf(wrow[c + 0], xr[c + 0], a0);
            a1 = fmaf(wrow[c + 1], xr[c + 1], a1);
            a2 = fmaf(wrow[c + 2], xr[c + 2], a2);
            a3 = fmaf(wrow[c + 3], xr[c + 3], a3);
        }
        acc[i] = (a0 + a1) + (a2 + a3);
    }

    // pack channel pairs -> zsu[point][o/2]; banks (lane+8w+i)%32 -> 2-way (free)
#pragma unroll
    for (int i = 0; i < 8; ++i)
        zsu[lane * 33 + w * 8 + i] =
            (unsigned)f2bf(acc[2 * i]) | ((unsigned)f2bf(acc[2 * i + 1]) << 16);
    __syncthreads();

    // coalesced store: thread t -> row t>>2, uints (t&3)*8..+7 (32B/thread)
    unsigned* zo = ztu + ((size_t)bl * NN + n0) * 32;
    const int r  = tid >> 2;
    const int c0 = (tid & 3) * 8;
    const unsigned* srow = &zsu[r * 33 + c0];
    uint4 v0, v1;
    v0.x = srow[0]; v0.y = srow[1]; v0.z = srow[2]; v0.w = srow[3];
    v1.x = srow[4]; v1.y = srow[5]; v1.z = srow[6]; v1.w = srow[7];
    *(uint4*)(zo + (size_t)r * 32 + c0)     = v0;
    *(uint4*)(zo + (size_t)r * 32 + c0 + 4) = v1;
}

// ---------------------------------------------------------------------------
// k3 (v2): h[b][o][n] = mean_k zt[b][e[b,n,k]][o], zt bf16x2-packed.
//   XCD-affinity: blockIdx.x & 7 selects XCD (dispatch round-robin heuristic);
//   batch = xcd & 3 -> each XCD's concurrent blocks gather from ONE 2 MB
//   batch slice, resident in that XCD's private 4 MB L2.
//   Lane map: lane>>5 = point parity (2 points/iter), lane&31 = channel pair.
//   Gather = one dword per lane -> 2 x 128B rows per instr. Indices loaded
//   once (coalesced 256B) and broadcast via readlane.
// ---------------------------------------------------------------------------
template <int ZB>
__global__ __launch_bounds__(256) void k3_gather(const unsigned* __restrict__ ztu,
                                                 const int* __restrict__ edges,
                                                 float* __restrict__ hout,
                                                 float* __restrict__ p1,
                                                 float* __restrict__ p2,
                                                 int b0) {
    __shared__ float otile[64 * 129];    // 33 KB, stride 129 (odd -> 2-way writes)
    __shared__ float red[4][64][4];      // 4 KB
    const int tid  = threadIdx.x;
    const int lane = tid & 63;
    const int w    = tid >> 6;
    int bl, chunk;
    if (ZB == 4) {
        const int xcd = blockIdx.x & 7;
        bl    = xcd & 3;                              // batch pinned per XCD
        chunk = ((xcd >> 2) << 6) + (blockIdx.x >> 3); // 0..127 within batch
    } else {
        bl = 0;
        chunk = blockIdx.x;                           // 128 blocks per batch
    }
    const int b  = b0 + bl;
    const int n0 = chunk << 7;                        // 128 points per block
    const unsigned* zb = ztu + (size_t)bl * NN * 32 + (lane & 31);
    const int hi = lane >> 5;                         // point parity
    float s1a = 0.f, s2a = 0.f, s1b = 0.f, s2b = 0.f;

#pragma unroll 4
    for (int i = 0; i < 16; ++i) {
        const int pl = w * 32 + 2 * i;                // even local point
        const int pg = b * NN + n0 + pl;              // global point
        const int my = edges[(size_t)pg * KK + lane]; // 2 points' 32+32 indices
        float a0 = 0.f, a1 = 0.f;
#pragma unroll
        for (int k = 0; k < KK; ++k) {
            const int e0 = __builtin_amdgcn_readlane(my, k);
            const int e1 = __builtin_amdgcn_readlane(my, 32 + k);
            const int e  = hi ? e1 : e0;
            const unsigned u = zb[(size_t)e * 32];    // 128B row, L2-resident
            a0 += bflo(u);                            // channel 2cp
            a1 += bfhi(u);                            // channel 2cp+1
        }
        const float h0 = a0 * (1.0f / KK);
        const float h1 = a1 * (1.0f / KK);
        s1a += h0; s2a += h0 * h0;
        s1b += h1; s2b += h1 * h1;
        const int pidx = pl + hi;
        const int cp   = lane & 31;
        otile[(2 * cp)     * 129 + pidx] = h0;
        otile[(2 * cp + 1) * 129 + pidx] = h1;
    }
    __syncthreads();

    // coalesced transposed store: thread t -> channel t>>2, cols (t&3)*32..+31
    {
        const int row = tid >> 2;
        const int c0  = (tid & 3) * 32;
        float* dst = hout + (size_t)b * CC * NN + (size_t)row * NN + n0 + c0;
#pragma unroll
        for (int j = 0; j < 32; j += 4) {
            float4 v;
            v.x = otile[row * 129 + c0 + j + 0];
            v.y = otile[row * 129 + c0 + j + 1];
            v.z = otile[row * 129 + c0 + j + 2];
            v.w = otile[row * 129 + c0 + j + 3];
            *(float4*)(dst + j) = v;
        }
    }

    // BN partials: channel c=2cp from a-regs, c=2cp+1 from b-regs
    red[w][lane][0] = s1a; red[w][lane][1] = s2a;
    red[w][lane][2] = s1b; red[w][lane][3] = s2b;
    __syncthreads();
    if (tid < 64) {
        const int cp = tid >> 1, sub = tid & 1;       // channel = tid
        float t1 = 0.f, t2 = 0.f;
#pragma unroll
        for (int w2 = 0; w2 < 4; ++w2) {
            t1 += red[w2][cp][2 * sub]     + red[w2][cp + 32][2 * sub];
            t2 += red[w2][cp][2 * sub + 1] + red[w2][cp + 32][2 * sub + 1];
        }
        const int pslot = (ZB == 4) ? (bl * 128 + chunk) : (b0 * 128 + chunk);
        p1[pslot * 64 + tid] = t1;
        p2[pslot * 64 + tid] = t2;
    }
}

// ---------------------------------------------------------------------------
// k4: reduce NB3 partials per channel -> scale/shift (biased var, eps=1e-5).
// ---------------------------------------------------------------------------
__global__ __launch_bounds__(1024) void k4_stats(const float* __restrict__ p1,
                                                 const float* __restrict__ p2,
                                                 const float* __restrict__ gamma,
                                                 const float* __restrict__ beta,
                                                 float* __restrict__ sc,
                                                 float* __restrict__ sh) {
    __shared__ float r1[1024], r2[1024];
    const int tid = threadIdx.x;
    float s1 = 0.f, s2 = 0.f;
    for (int i = tid; i < NB3 * 64; i += 1024) {  // channel = i & 63 constant/thread
        s1 += p1[i];
        s2 += p2[i];
    }
    r1[tid] = s1;
    r2[tid] = s2;
    __syncthreads();
    if (tid < 64) {
        float t1 = 0.f, t2 = 0.f;
#pragma unroll
        for (int j = 0; j < 1024; j += 64) { t1 += r1[tid + j]; t2 += r2[tid + j]; }
        const float inv = 1.0f / (float)PTS;
        const float mu  = t1 * inv;
        const float var = t2 * inv - mu * mu;     // biased variance (torch BN)
        const float s   = gamma[tid] * rsqrtf(var + 1e-5f);
        sc[tid] = s;
        sh[tid] = beta[tid] - mu * s;
    }
}

// ---------------------------------------------------------------------------
// k5: in-place BN apply + LeakyReLU(0.2) on d_out, float4 vectorized.
// ---------------------------------------------------------------------------
__global__ __launch_bounds__(256) void k5_bn(float* __restrict__ out,
                                             const float* __restrict__ sc,
                                             const float* __restrict__ sh) {
    const int total4 = BB * CC * NN / 4;          // 1,048,576 float4
    for (int i = blockIdx.x * 256 + threadIdx.x; i < total4; i += gridDim.x * 256) {
        const int c = (i >> 12) & 63;             // N/4 = 4096 float4 per channel
        const float s = sc[c];
        const float t = sh[c];
        float4 v = ((const float4*)out)[i];
        float y;
        y = fmaf(v.x, s, t); v.x = y > 0.f ? y : 0.2f * y;
        y = fmaf(v.y, s, t); v.y = y > 0.f ? y : 0.2f * y;
        y = fmaf(v.z, s, t); v.z = y > 0.f ? y : 0.2f * y;
        y = fmaf(v.w, s, t); v.w = y > 0.f ? y : 0.2f * y;
        ((float4*)out)[i] = v;
    }
}

extern "C" void kernel_launch(void* const* d_in, const int* in_sizes, int n_in,
                              void* d_out, int out_size, void* d_ws, size_t ws_size,
                              hipStream_t stream) {
    const float* x     = (const float*)d_in[0];
    const int*   edges = (const int*)d_in[1];      // harness: integer inputs -> int32
    const float* W     = (const float*)d_in[2];
    const float* gamma = (const float*)d_in[3];
    const float* beta  = (const float*)d_in[4];
    float* out = (float*)d_out;

    const size_t ZT_FULL_U = (size_t)BB * NN * 32;          // bf16x2 uints, 8.4 MB
    const size_t ZT_ONE_U  = (size_t)NN * 32;               // 2.1 MB
    const size_t PARTS_F   = (size_t)NB3 * 64 * 2 + 128;    // p1+p2+sc+sh
    const bool full = ws_size >= (ZT_FULL_U + PARTS_F) * 4;

    unsigned* ztu = (unsigned*)d_ws;
    float* p1 = (float*)d_ws + (full ? ZT_FULL_U : ZT_ONE_U);
    float* p2 = p1 + (size_t)NB3 * 64;
    float* sc = p2 + (size_t)NB3 * 64;
    float* sh = sc + 64;

    if (full) {
        hipLaunchKernelGGL((k1_wx_t<BB>),   dim3(BB * 256), dim3(256), 0, stream,
                           x, W, ztu, 0);
        hipLaunchKernelGGL((k3_gather<BB>), dim3(BB * 128), dim3(256), 0, stream,
                           ztu, edges, out, p1, p2, 0);
    } else {
        for (int b = 0; b < BB; ++b) {
            hipLaunchKernelGGL((k1_wx_t<1>),   dim3(256), dim3(256), 0, stream,
                               x, W, ztu, b);
            hipLaunchKernelGGL((k3_gather<1>), dim3(128), dim3(256), 0, stream,
                               ztu, edges, out, p1, p2, b);
        }
    }
    hipLaunchKernelGGL(k4_stats, dim3(1), dim3(1024), 0, stream, p1, p2, gamma, beta, sc, sh);
    hipLaunchKernelGGL(k5_bn, dim3(2048), dim3(256), 0, stream, out, sc, sh);
}

// Round 10
// 173.407 us; speedup vs baseline: 1.2948x; 1.2948x over previous
//
#include <hip/hip_runtime.h>
#include <hip/hip_bf16.h>

// Problem constants (GraphConv: B=4, C=64, N=16384, K=32)
#define BB 4
#define CC 64
#define NN 16384
#define KK 32
#define PTS (BB * NN)   // 65536 points
#define NP  2048        // BN partial slots (32 points each)

// ---- bf16 helpers (RNE pack, cheap unpack) --------------------------------
static __device__ __forceinline__ unsigned short f2bf(float f) {
    unsigned u = __builtin_bit_cast(unsigned, f);
    unsigned r = (u + 0x7fffu + ((u >> 16) & 1u)) >> 16;   // round-nearest-even
    return (unsigned short)r;
}
static __device__ __forceinline__ float bflo(unsigned u) {
    return __builtin_bit_cast(float, u << 16);
}
static __device__ __forceinline__ float bfhi(unsigned u) {
    return __builtin_bit_cast(float, u & 0xffff0000u);
}

// ---------------------------------------------------------------------------
// k1 (v3, unchanged control): zt[bl][n][o] (bf16x2) = sum_c W[o][c]*x[b][c][n].
// ---------------------------------------------------------------------------
template <int ZB>
__global__ __launch_bounds__(256) void k1_wx_t(const float* __restrict__ x,
                                               const float* __restrict__ W,
                                               unsigned* __restrict__ ztu,
                                               int b0) {
    __shared__ float    xs[64 * 65];     // 16.6 KB
    __shared__ unsigned zsu[64 * 33];    // 8.4 KB (point-major, bf16x2)
    const int tid  = threadIdx.x;
    const int lane = tid & 63;
    const int w    = tid >> 6;
    const int chunk = blockIdx.x;        // ZB*256 chunks of 64 points
    const int bl = chunk >> 8;           // local batch
    const int b  = b0 + bl;              // global batch
    const int n0 = (chunk & 255) << 6;

    const float* xb = x + (size_t)b * CC * NN + n0;
#pragma unroll
    for (int i = 0; i < 16; ++i) {
        const int c = i * 4 + w;
        xs[c * 65 + lane] = xb[(size_t)c * NN + lane];
    }
    __syncthreads();

    float xr[64];
#pragma unroll
    for (int c = 0; c < 64; ++c) xr[c] = xs[c * 65 + lane];

    float acc[16];
#pragma unroll
    for (int i = 0; i < 16; ++i) {
        const int o = w * 16 + i;
        const unsigned long long wa = (unsigned long long)(const void*)(W + (o << 6));
        const unsigned plo = __builtin_amdgcn_readfirstlane((unsigned)wa);
        const unsigned phi = __builtin_amdgcn_readfirstlane((unsigned)(wa >> 32));
        const float* wrow = (const float*)(((unsigned long long)phi << 32) | plo);
        float a0 = 0.f, a1 = 0.f, a2 = 0.f, a3 = 0.f;
#pragma unroll
        for (int c = 0; c < 64; c += 4) {
            a0 = fmaf(wrow[c + 0], xr[c + 0], a0);
            a1 = fmaf(wrow[c + 1], xr[c + 1], a1);
            a2 = fmaf(wrow[c + 2], xr[c + 2], a2);
            a3 = fmaf(wrow[c + 3], xr[c + 3], a3);
        }
        acc[i] = (a0 + a1) + (a2 + a3);
    }

#pragma unroll
    for (int i = 0; i < 8; ++i)
        zsu[lane * 33 + w * 8 + i] =
            (unsigned)f2bf(acc[2 * i]) | ((unsigned)f2bf(acc[2 * i + 1]) << 16);
    __syncthreads();

    unsigned* zo = ztu + ((size_t)bl * NN + n0) * 32;
    const int r  = tid >> 2;
    const int c0 = (tid & 3) * 8;
    const unsigned* srow = &zsu[r * 33 + c0];
    uint4 v0, v1;
    v0.x = srow[0]; v0.y = srow[1]; v0.z = srow[2]; v0.w = srow[3];
    v1.x = srow[4]; v1.y = srow[5]; v1.z = srow[6]; v1.w = srow[7];
    *(uint4*)(zo + (size_t)r * 32 + c0)     = v0;
    *(uint4*)(zo + (size_t)r * 32 + c0 + 4) = v1;
}

// ---------------------------------------------------------------------------
// k3 (v3): latency-hiding rework. 2048 blocks x 32 points (8 blocks/CU) +
//   explicit 8-deep gather ILP (8 independent loads in flight per wave; the
//   rolled v2 loop serialized on vmcnt(0) per load -> 110us latency-bound).
//   XCD pinning kept (FETCH 205->12.4 MB proved it): xcd = bid&7, batch=xcd&3,
//   zt slice 2 MB bf16 resident in that XCD's 4 MB L2.
//   Edge rows for the wave's 8 points prefetched upfront (one HBM latency).
// ---------------------------------------------------------------------------
template <int ZB>
__global__ __launch_bounds__(256) void k3_gather(const unsigned* __restrict__ ztu,
                                                 const int* __restrict__ edges,
                                                 float* __restrict__ hout,
                                                 float* __restrict__ p1,
                                                 float* __restrict__ p2,
                                                 int b0) {
    __shared__ float otile[64 * 33];     // 8.4 KB (channel-major, 32 points)
    __shared__ float red[4][64][4];      // 4 KB
    const int tid  = threadIdx.x;
    const int lane = tid & 63;
    const int w    = tid >> 6;
    int bl, chunk;
    if (ZB == 4) {
        const int xcd = blockIdx.x & 7;
        bl    = xcd & 3;                               // batch pinned per XCD
        chunk = (((blockIdx.x >> 2) & 1) << 8) | (blockIdx.x >> 3);  // 0..511
    } else {
        bl = 0;
        chunk = blockIdx.x;                            // 512 blocks per batch
    }
    const int b  = b0 + bl;
    const int n0 = chunk << 5;                         // 32 points per block
    const unsigned* zb = ztu + (size_t)bl * NN * 32 + (lane & 31);
    const int hi = lane >> 5;                          // point parity
    float s1a = 0.f, s2a = 0.f, s1b = 0.f, s2b = 0.f;

    // prefetch all edge rows for this wave's 8 points (4 x 256B coalesced)
    const int pg0 = b * NN + n0 + w * 8;
    int myv[4];
#pragma unroll
    for (int i = 0; i < 4; ++i)
        myv[i] = edges[(size_t)(pg0 + 2 * i) * KK + lane];

#pragma unroll
    for (int i = 0; i < 4; ++i) {
        const int my = myv[i];
        float a0 = 0.f, a1 = 0.f;
#pragma unroll
        for (int kk = 0; kk < KK; kk += 8) {
            int e[8];
#pragma unroll
            for (int j = 0; j < 8; ++j) {
                const int e0 = __builtin_amdgcn_readlane(my, kk + j);
                const int e1 = __builtin_amdgcn_readlane(my, 32 + kk + j);
                e[j] = hi ? e1 : e0;
            }
            unsigned u[8];
#pragma unroll
            for (int j = 0; j < 8; ++j) u[j] = zb[(size_t)e[j] * 32];  // 8 in flight
#pragma unroll
            for (int j = 0; j < 8; ++j) { a0 += bflo(u[j]); a1 += bfhi(u[j]); }
        }
        const float h0 = a0 * (1.0f / KK);
        const float h1 = a1 * (1.0f / KK);
        s1a += h0; s2a += h0 * h0;
        s1b += h1; s2b += h1 * h1;
        const int pidx = w * 8 + 2 * i + hi;
        const int cp   = lane & 31;
        otile[(2 * cp)     * 33 + pidx] = h0;          // 2-way banks = free
        otile[(2 * cp + 1) * 33 + pidx] = h1;
    }
    __syncthreads();

    // coalesced transposed store: thread t -> channel t>>2, cols (t&3)*8..+7
    {
        const int row = tid >> 2;
        const int c0  = (tid & 3) * 8;
        const float* s = &otile[row * 33 + c0];
        float4 v0, v1;
        v0.x = s[0]; v0.y = s[1]; v0.z = s[2]; v0.w = s[3];
        v1.x = s[4]; v1.y = s[5]; v1.z = s[6]; v1.w = s[7];
        float* dst = hout + (size_t)b * CC * NN + (size_t)row * NN + n0 + c0;
        *(float4*)dst       = v0;
        *(float4*)(dst + 4) = v1;
    }

    // BN partials
    red[w][lane][0] = s1a; red[w][lane][1] = s2a;
    red[w][lane][2] = s1b; red[w][lane][3] = s2b;
    __syncthreads();
    if (tid < 64) {
        const int cp = tid >> 1, sub = tid & 1;        // channel = tid
        float t1 = 0.f, t2 = 0.f;
#pragma unroll
        for (int w2 = 0; w2 < 4; ++w2) {
            t1 += red[w2][cp][2 * sub]     + red[w2][cp + 32][2 * sub];
            t2 += red[w2][cp][2 * sub + 1] + red[w2][cp + 32][2 * sub + 1];
        }
        const int pslot = (ZB == 4) ? (bl * 512 + chunk) : (b0 * 512 + chunk);
        p1[pslot * 64 + tid] = t1;
        p2[pslot * 64 + tid] = t2;
    }
}

// ---------------------------------------------------------------------------
// k4: reduce NP partials per channel -> scale/shift (biased var, eps=1e-5).
// ---------------------------------------------------------------------------
__global__ __launch_bounds__(1024) void k4_stats(const float* __restrict__ p1,
                                                 const float* __restrict__ p2,
                                                 const float* __restrict__ gamma,
                                                 const float* __restrict__ beta,
                                                 float* __restrict__ sc,
                                                 float* __restrict__ sh) {
    __shared__ float r1[1024], r2[1024];
    const int tid = threadIdx.x;
    float s1 = 0.f, s2 = 0.f;
    for (int i = tid; i < NP * 64; i += 1024) {   // channel = i & 63 constant/thread
        s1 += p1[i];
        s2 += p2[i];
    }
    r1[tid] = s1;
    r2[tid] = s2;
    __syncthreads();
    if (tid < 64) {
        float t1 = 0.f, t2 = 0.f;
#pragma unroll
        for (int j = 0; j < 1024; j += 64) { t1 += r1[tid + j]; t2 += r2[tid + j]; }
        const float inv = 1.0f / (float)PTS;
        const float mu  = t1 * inv;
        const float var = t2 * inv - mu * mu;      // biased variance (torch BN)
        const float s   = gamma[tid] * rsqrtf(var + 1e-5f);
        sc[tid] = s;
        sh[tid] = beta[tid] - mu * s;
    }
}

// ---------------------------------------------------------------------------
// k5: in-place BN apply + LeakyReLU(0.2) on d_out, float4 vectorized.
// ---------------------------------------------------------------------------
__global__ __launch_bounds__(256) void k5_bn(float* __restrict__ out,
                                             const float* __restrict__ sc,
                                             const float* __restrict__ sh) {
    const int total4 = BB * CC * NN / 4;           // 1,048,576 float4
    for (int i = blockIdx.x * 256 + threadIdx.x; i < total4; i += gridDim.x * 256) {
        const int c = (i >> 12) & 63;              // N/4 = 4096 float4 per channel
        const float s = sc[c];
        const float t = sh[c];
        float4 v = ((const float4*)out)[i];
        float y;
        y = fmaf(v.x, s, t); v.x = y > 0.f ? y : 0.2f * y;
        y = fmaf(v.y, s, t); v.y = y > 0.f ? y : 0.2f * y;
        y = fmaf(v.z, s, t); v.z = y > 0.f ? y : 0.2f * y;
        y = fmaf(v.w, s, t); v.w = y > 0.f ? y : 0.2f * y;
        ((float4*)out)[i] = v;
    }
}

extern "C" void kernel_launch(void* const* d_in, const int* in_sizes, int n_in,
                              void* d_out, int out_size, void* d_ws, size_t ws_size,
                              hipStream_t stream) {
    const float* x     = (const float*)d_in[0];
    const int*   edges = (const int*)d_in[1];      // harness: integer inputs -> int32
    const float* W     = (const float*)d_in[2];
    const float* gamma = (const float*)d_in[3];
    const float* beta  = (const float*)d_in[4];
    float* out = (float*)d_out;

    const size_t ZT_FULL_U = (size_t)BB * NN * 32;          // bf16x2 uints, 8.4 MB
    const size_t ZT_ONE_U  = (size_t)NN * 32;               // 2.1 MB
    const size_t PARTS_F   = (size_t)NP * 64 * 2 + 128;     // p1+p2+sc+sh
    const bool full = ws_size >= (ZT_FULL_U + PARTS_F) * 4;

    unsigned* ztu = (unsigned*)d_ws;
    float* p1 = (float*)d_ws + (full ? ZT_FULL_U : ZT_ONE_U);
    float* p2 = p1 + (size_t)NP * 64;
    float* sc = p2 + (size_t)NP * 64;
    float* sh = sc + 64;

    if (full) {
        hipLaunchKernelGGL((k1_wx_t<BB>),   dim3(BB * 256), dim3(256), 0, stream,
                           x, W, ztu, 0);
        hipLaunchKernelGGL((k3_gather<BB>), dim3(2048), dim3(256), 0, stream,
                           ztu, edges, out, p1, p2, 0);
    } else {
        for (int b = 0; b < BB; ++b) {
            hipLaunchKernelGGL((k1_wx_t<1>),   dim3(256), dim3(256), 0, stream,
                               x, W, ztu, b);
            hipLaunchKernelGGL((k3_gather<1>), dim3(512), dim3(256), 0, stream,
                               ztu, edges, out, p1, p2, b);
        }
    }
    hipLaunchKernelGGL(k4_stats, dim3(1), dim3(1024), 0, stream, p1, p2, gamma, beta, sc, sh);
    hipLaunchKernelGGL(k5_bn, dim3(2048), dim3(256), 0, stream, out, sc, sh);
}